// Round 1
// baseline (79.929 us; speedup 1.0000x reference)
//
#include <hip/hip_runtime.h>

// Problem constants (from reference): B=64, CIN=64, COUT=64, K=3, H=W=112, PAD=1
// Reference uses ONLY the last input channel (index CIN-1) and the matching
// weight slice: out[b,co,h,w] = bias[co] + sum_{kh,kw} x[b,63,h+kh,w+kw]*wt[co,63,kh,kw]

#define CB   64
#define CCIN 64
#define CCOUT 64
#define CH   112
#define CW   112
#define CHP  114
#define CWP  114

__global__ __launch_bounds__(256) void CustomConv2D_12953621365171_kernel(
    const float* __restrict__ x,      // (B, CIN, 114, 114)
    const float* __restrict__ wt,     // (COUT, CIN, 3, 3)
    const float* __restrict__ bias,   // (COUT,)
    float* __restrict__ out)          // (B, COUT, 112, 112)
{
    const int WV = CW / 4;  // 28 float4 groups per row
    long long idx = (long long)blockIdx.x * blockDim.x + threadIdx.x;
    const long long total = (long long)CB * CCOUT * CH * WV;
    if (idx >= total) return;

    int wv = (int)(idx % WV);
    long long t = idx / WV;
    int h  = (int)(t % CH);
    t /= CH;
    int co = (int)(t % CCOUT);
    int b  = (int)(t / CCOUT);

    const int w0 = wv * 4;

    // channel-63 slice of x for this batch
    const float* xs = x + ((long long)b * CCIN + (CCIN - 1)) * (CHP * CWP);
    // channel-63 weight slice for this cout (wave-uniform -> scalar loads)
    const float* wp = wt + ((long long)co * CCIN + (CCIN - 1)) * 9;

    float bv = bias[co];
    float a0 = bv, a1 = bv, a2 = bv, a3 = bv;

    #pragma unroll
    for (int kh = 0; kh < 3; ++kh) {
        const float* row = xs + (h + kh) * CWP + w0;
        float r0 = row[0], r1 = row[1], r2 = row[2];
        float r3 = row[3], r4 = row[4], r5 = row[5];
        float k0 = wp[kh * 3 + 0], k1 = wp[kh * 3 + 1], k2 = wp[kh * 3 + 2];
        a0 = fmaf(k0, r0, fmaf(k1, r1, fmaf(k2, r2, a0)));
        a1 = fmaf(k0, r1, fmaf(k1, r2, fmaf(k2, r3, a1)));
        a2 = fmaf(k0, r2, fmaf(k1, r3, fmaf(k2, r4, a2)));
        a3 = fmaf(k0, r3, fmaf(k1, r4, fmaf(k2, r5, a3)));
    }

    float4 o = make_float4(a0, a1, a2, a3);
    *reinterpret_cast<float4*>(out + idx * 4) = o;
}

extern "C" void kernel_launch(void* const* d_in, const int* in_sizes, int n_in,
                              void* d_out, int out_size, void* d_ws, size_t ws_size,
                              hipStream_t stream) {
    const float* x    = (const float*)d_in[0];
    const float* wt   = (const float*)d_in[1];
    const float* bias = (const float*)d_in[2];
    float* out = (float*)d_out;

    const long long total = (long long)CB * CCOUT * CH * (CW / 4); // 12,845,056 threads
    const int block = 256;
    const long long grid = (total + block - 1) / block;            // 50,176 blocks

    CustomConv2D_12953621365171_kernel<<<(unsigned)grid, block, 0, stream>>>(x, wt, bias, out);
}

// Round 2
// 39.653 us; speedup vs baseline: 2.0157x; 2.0157x over previous
//
#include <hip/hip_runtime.h>

// Reference uses ONLY the last input channel (CIN-1) and matching weight slice:
// out[b,co,h,w] = bias[co] + sum_{kh,kw} x[b,63,h+kh,w+kw] * wt[co,63,kh,kw]
// Shapes: x (64,64,114,114) f32, wt (64,64,3,3) f32, bias (64) f32,
//         out (64,64,112,112) f32 (205.5 MB) -> write-BW bound, floor ~30us.

#define CB    64
#define CCIN  64
#define CCOUT 64
#define CH    112
#define CW    112
#define CHP   114
#define CWP   114
#define NCO   4          // co values per thread (x-data reuse)
#define SPT   (CH * (CW/4))   // 3136 spatial float4-groups per (b,co) plane

__global__ __launch_bounds__(256) void CustomConv2D_12953621365171_kernel(
    const float* __restrict__ x,      // (B, CIN, 114, 114)
    const float* __restrict__ wt,     // (COUT, CIN, 3, 3)
    const float* __restrict__ bias,   // (COUT,)
    float* __restrict__ out)          // (B, COUT, 112, 112)
{
    int s = blockIdx.x * 256 + threadIdx.x;       // spatial: h*28 + wv
    if (s >= SPT) return;
    const int co0 = blockIdx.y * NCO;             // block-uniform -> SGPR
    const int b   = blockIdx.z;                   // block-uniform -> SGPR

    int h  = s / 28;                              // 32-bit magic-mul div
    int wv = s - h * 28;
    int w0 = wv * 4;

    // channel-63 x slice for this batch (uniform base + per-lane offset)
    const float* xs = x + ((size_t)b * CCIN + (CCIN - 1)) * (CHP * CWP);

    // Weights & bias: addresses depend only on blockIdx -> scalar loads
    float wk[NCO][9];
    float bv[NCO];
    #pragma unroll
    for (int j = 0; j < NCO; ++j) {
        const float* wp = wt + ((size_t)(co0 + j) * CCIN + (CCIN - 1)) * 9;
        #pragma unroll
        for (int t = 0; t < 9; ++t) wk[j][t] = wp[t];
        bv[j] = bias[co0 + j];
    }

    float acc[NCO][4];
    #pragma unroll
    for (int j = 0; j < NCO; ++j) {
        acc[j][0] = bv[j]; acc[j][1] = bv[j]; acc[j][2] = bv[j]; acc[j][3] = bv[j];
    }

    #pragma unroll
    for (int kh = 0; kh < 3; ++kh) {
        const float* row = xs + (h + kh) * CWP + w0;
        float r0 = row[0], r1 = row[1], r2 = row[2];
        float r3 = row[3], r4 = row[4], r5 = row[5];
        #pragma unroll
        for (int j = 0; j < NCO; ++j) {
            float k0 = wk[j][kh * 3 + 0];
            float k1 = wk[j][kh * 3 + 1];
            float k2 = wk[j][kh * 3 + 2];
            acc[j][0] = fmaf(k0, r0, fmaf(k1, r1, fmaf(k2, r2, acc[j][0])));
            acc[j][1] = fmaf(k0, r1, fmaf(k1, r2, fmaf(k2, r3, acc[j][1])));
            acc[j][2] = fmaf(k0, r2, fmaf(k1, r3, fmaf(k2, r4, acc[j][2])));
            acc[j][3] = fmaf(k0, r3, fmaf(k1, r4, fmaf(k2, r5, acc[j][3])));
        }
    }

    // out offset for (b, co0+j, h, w0) = plane*12544 + (h*112 + wv*4) = plane*12544 + s*4
    #pragma unroll
    for (int j = 0; j < NCO; ++j) {
        float4 o = make_float4(acc[j][0], acc[j][1], acc[j][2], acc[j][3]);
        size_t off = ((size_t)b * CCOUT + (co0 + j)) * (CH * CW) + (size_t)s * 4;
        *reinterpret_cast<float4*>(out + off) = o;
    }
}

extern "C" void kernel_launch(void* const* d_in, const int* in_sizes, int n_in,
                              void* d_out, int out_size, void* d_ws, size_t ws_size,
                              hipStream_t stream) {
    const float* x    = (const float*)d_in[0];
    const float* wt   = (const float*)d_in[1];
    const float* bias = (const float*)d_in[2];
    float* out = (float*)d_out;

    dim3 grid((SPT + 255) / 256,      // 13 blocks (last partially active)
              CCOUT / NCO,            // 16
              CB);                    // 64
    dim3 block(256, 1, 1);

    CustomConv2D_12953621365171_kernel<<<grid, block, 0, stream>>>(x, wt, bias, out);
}